// Round 1
// baseline (602.008 us; speedup 1.0000x reference)
//
#include <hip/hip_runtime.h>
#include <hip/hip_fp8.h>

typedef unsigned short u16;
typedef unsigned char  u8;
typedef long long      i64;
using bf16x8 = __attribute__((ext_vector_type(8))) __bf16;
using f32x4  = __attribute__((ext_vector_type(4))) float;

__device__ __forceinline__ u16 f2bf(float f) {
    unsigned u = __builtin_bit_cast(unsigned, f);
    u += 0x7fffu + ((u >> 16) & 1u);
    return (u16)(u >> 16);
}
__device__ __forceinline__ float bf2f(u16 h) {
    unsigned u = ((unsigned)h) << 16;
    return __builtin_bit_cast(float, u);
}
__device__ __forceinline__ u8 f2fp8(float f) {
    __hip_fp8_e4m3 t(f);
    return t.__x;
}
__device__ __forceinline__ float wred_sum(float v) {
    #pragma unroll
    for (int o = 32; o; o >>= 1) v += __shfl_xor(v, o, 64);
    return v;
}

// async global->LDS, 16B per lane. LDS dest must be wave-uniform base + lane*16.
__device__ __forceinline__ void gl2lds16(const void* g, void* l) {
    __builtin_amdgcn_global_load_lds(
        (__attribute__((address_space(1))) void*)(g),
        (__attribute__((address_space(3))) void*)(l), 16, 0, 0);
}

// ---------------------------------------------------------------- cast fp32->bf16
__global__ __launch_bounds__(256)
void cast_bf16(const float* __restrict__ src, u16* __restrict__ dst, int n4) {
    int i = blockIdx.x * 256 + threadIdx.x;
    if (i < n4) {
        float4 f = ((const float4*)src)[i];
        ushort4 u;
        u.x = f2bf(f.x); u.y = f2bf(f.y); u.z = f2bf(f.z); u.w = f2bf(f.w);
        ((ushort4*)dst)[i] = u;
    }
}

// ---------------------------------------------------------------- cast bf16 -> fp8 e4m3 (8 elems/thread)
__global__ __launch_bounds__(256)
void cast_v_fp8(const u16* __restrict__ src, u8* __restrict__ dst, int n8) {
    int i = blockIdx.x * 256 + threadIdx.x;
    if (i < n8) {
        ushort4 a = ((const ushort4*)src)[2 * i];
        ushort4 b = ((const ushort4*)src)[2 * i + 1];
        union { u8 c[8]; unsigned long long q; } r;
        r.c[0] = f2fp8(bf2f(a.x)); r.c[1] = f2fp8(bf2f(a.y));
        r.c[2] = f2fp8(bf2f(a.z)); r.c[3] = f2fp8(bf2f(a.w));
        r.c[4] = f2fp8(bf2f(b.x)); r.c[5] = f2fp8(bf2f(b.y));
        r.c[6] = f2fp8(bf2f(b.z)); r.c[7] = f2fp8(bf2f(b.w));
        ((unsigned long long*)dst)[i] = r.q;
    }
}

// ---------------------------------------------------------------- GEMM C = A * Bt^T (bf16) — QKV projection only
// (unchanged 128-tile structure; next optimization target)
template<int MODE, int TM, bool SWAP>
__global__ __launch_bounds__(256, 4)
void gemm_bt(const u16* __restrict__ A, const u16* __restrict__ Bt, const int K,
             u16* __restrict__ oQ, u16* __restrict__ oK, u16* __restrict__ oVt,
             const float* __restrict__ bQ, const float* __restrict__ bK,
             const float* __restrict__ bV,
             u8* __restrict__ oP, float* __restrict__ sums, const float scale)
{
    __shared__ u16 smem[TM * 32 + 128 * 32];
    u16* As = smem;
    u16* Bs = smem + TM * 32;

    constexpr int IM = TM / 32;
    const int tid  = threadIdx.x;
    const int wv   = tid >> 6;
    const int lane = tid & 63;
    const int wr   = (wv >> 1) * (TM / 2);
    const int wc   = (wv & 1) << 6;

    const int row0 = (SWAP ? blockIdx.x : blockIdx.y) * TM;
    const int col0 = (SWAP ? blockIdx.y : blockIdx.x) * 128;

    const int srow = tid >> 2;
    const int scol = (((tid & 3) ^ ((tid >> 3) & 3)) << 3);

    const u16* pA0 = A  + (size_t)(row0 + srow) * K + scol;
    const u16* pB0 = Bt + (size_t)(col0 + srow) * K + scol;

    char* aB0 = (char*)As + wv * 1024;
    char* aB1 = (char*)As + 4096 + wv * 1024;
    char* bB0 = (char*)Bs + wv * 1024;
    char* bB1 = (char*)Bs + 4096 + wv * 1024;

    const int fr = lane & 15;
    const int g  = lane >> 4;
    const int sw = (fr >> 1) & 3;
    const int kc = ((g ^ sw) << 3);

    f32x4 acc[IM][4];
    #pragma unroll
    for (int i = 0; i < IM; i++)
        #pragma unroll
        for (int j = 0; j < 4; j++) acc[i][j] = (f32x4){0.f, 0.f, 0.f, 0.f};

    for (int k0 = 0; k0 < K; k0 += 32) {
        __syncthreads();
        gl2lds16(pA0 + k0, aB0);
        if (TM == 128) gl2lds16(pA0 + (size_t)64 * K + k0, aB1);
        gl2lds16(pB0 + k0, bB0);
        gl2lds16(pB0 + (size_t)64 * K + k0, bB1);
        __syncthreads();

        bf16x8 af[IM], bfr[4];
        #pragma unroll
        for (int i = 0; i < IM; i++) af[i]  = *(const bf16x8*)&As[(wr + 16 * i + fr) * 32 + kc];
        #pragma unroll
        for (int j = 0; j < 4; j++)  bfr[j] = *(const bf16x8*)&Bs[(wc + 16 * j + fr) * 32 + kc];
        #pragma unroll
        for (int i = 0; i < IM; i++)
            #pragma unroll
            for (int j = 0; j < 4; j++)
                acc[i][j] = __builtin_amdgcn_mfma_f32_16x16x32_bf16(af[i], bfr[j], acc[i][j], 0, 0, 0);
    }

    const int rB = (lane >> 4) << 2;
    const int cB = lane & 15;

    if (MODE == 0) {
        const int sel = col0 >> 10;     // 0=Q 1=K 2=V
        if (sel < 2) {
            const float* bias = (sel == 0) ? bQ : bK;
            u16* dst = (sel == 0) ? oQ : oK;
            #pragma unroll
            for (int i = 0; i < IM; i++) {
                #pragma unroll
                for (int j = 0; j < 4; j++) {
                    const int m0 = row0 + wr + 16 * i + rB;
                    const int e  = (col0 & 1023) + wc + 16 * j + cB;
                    const float bb = bias[e];
                    #pragma unroll
                    for (int t = 0; t < 4; t++)
                        dst[(size_t)(m0 + t) * 1024 + e] = f2bf(acc[i][j][t] + bb);
                }
            }
        } else {
            const int b      = row0 >> 12;
            const int n_base = row0 & 4095;
            const int e0     = col0 & 1023;
            __syncthreads();
            #pragma unroll
            for (int P = 0; P < 2; ++P) {
                if ((wc >> 6) == P) {
                    #pragma unroll
                    for (int i = 0; i < IM; i++) {
                        const int n_l0 = wr + 16 * i + rB;
                        const int hq   = n_l0 >> 3;
                        const int off  = n_l0 & 7;
                        #pragma unroll
                        for (int j = 0; j < 4; j++) {
                            const int e_p = 16 * j + cB;
                            const int hp  = hq ^ (e_p & 7);
                            const float bb = bV[e0 + P * 64 + e_p];
                            ushort4 pk;
                            pk.x = f2bf(acc[i][j][0] + bb);
                            pk.y = f2bf(acc[i][j][1] + bb);
                            pk.z = f2bf(acc[i][j][2] + bb);
                            pk.w = f2bf(acc[i][j][3] + bb);
                            *(ushort4*)&smem[e_p * 128 + hp * 8 + off] = pk;
                        }
                    }
                }
                __syncthreads();
                #pragma unroll
                for (int p4 = 0; p4 < 4; ++p4) {
                    const int idx = p4 * 256 + tid;
                    const int er  = idx >> 4;
                    const int c   = idx & 15;
                    const int cc  = c ^ (er & 7);
                    int4 v = *(const int4*)&smem[er * 128 + cc * 8];
                    *(int4*)&oVt[(size_t)b * 4194304 +
                                 (size_t)(e0 + P * 64 + er) * 4096 + n_base + c * 8] = v;
                }
                if (P == 0) __syncthreads();
            }
        }
    }
}

// ---------------------------------------------------------------- S = exp(Q K^T * scale) -> fp8 P + row sums
// 256x256 tile, 512 threads (8 waves 2x4), BK=32, ring-4 LDS (128 KiB), counted vmcnt(8),
// raw s_barrier (no drain), setprio around MFMA clusters. Per-wave output 128x64.
// Prefetch for tile t+3 targets the slot retired at tile t-1 (protected by the tile-top barrier).
__global__ __launch_bounds__(512, 2)
void gemm_s8(const u16* __restrict__ Q, const u16* __restrict__ Km,
             u8* __restrict__ P, float* __restrict__ sm, const float scale)
{
    __shared__ u16 smem[65536];     // 128 KiB = 4 ring slots x (A 16KB + B 16KB)
    const int tid = threadIdx.x;
    const int wv = tid >> 6, lane = tid & 63;
    const int wm = wv >> 2, wn = wv & 3;
    const int row0 = blockIdx.x << 8, col0 = blockIdx.y << 8;

    const int srow = tid >> 2;                               // 0..127
    const int scol = ((tid & 3) ^ ((tid >> 3) & 3)) << 3;    // swizzled 16B chunk (elems)
    const u16* gA = Q  + (size_t)(row0 + srow) * 1024 + scol;
    const u16* gB = Km + (size_t)(col0 + srow) * 1024 + scol;
    char* lds = (char*)smem;
    const int wvo = wv << 10;

    const int fr = lane & 15, g = lane >> 4;
    const int kc = (g ^ ((fr >> 1) & 3)) << 4;               // swizzled chunk byte offset

    f32x4 acc[8][4];
    #pragma unroll
    for (int i = 0; i < 8; i++)
        #pragma unroll
        for (int j = 0; j < 4; j++) acc[i][j] = (f32x4){0.f, 0.f, 0.f, 0.f};

    // one K-tile stage = 4 gl2lds per wave: A rows 0-127 / 128-255, B rows 0-127 / 128-255
    #define SG_A(ts, sl) { \
        gl2lds16(gA + (ts) * 32,          lds + (sl) * 32768 + wvo); \
        gl2lds16(gA + 131072 + (ts) * 32, lds + (sl) * 32768 + 8192 + wvo); }
    #define SG_B(ts, sl) { \
        gl2lds16(gB + (ts) * 32,          lds + (sl) * 32768 + 16384 + wvo); \
        gl2lds16(gB + 131072 + (ts) * 32, lds + (sl) * 32768 + 24576 + wvo); }

    SG_A(0, 0); SG_B(0, 0);
    SG_A(1, 1); SG_B(1, 1);
    SG_A(2, 2); SG_B(2, 2);

    for (int t = 0; t < 32; ++t) {
        const int slot = t & 3;
        const int ts = (t + 3) & 31;      // wraps to 0..2 at the tail: redundant but safe
        const int ns = (t + 3) & 3;
        const char* Ab = lds + slot * 32768;
        const char* Bb = Ab + 16384;

        // tile t's 4 loads are the oldest of 12 outstanding -> vmcnt(8), never 0.
        asm volatile("s_waitcnt vmcnt(8)" ::: "memory");
        __builtin_amdgcn_s_barrier();
        __builtin_amdgcn_sched_barrier(0);

        // phase 0: rows 0..63 of the wave's 128
        SG_A(ts, ns);
        bf16x8 bf[4], af[4];
        #pragma unroll
        for (int j = 0; j < 4; ++j)
            bf[j] = *(const bf16x8*)(Bb + (wn * 64 + 16 * j + fr) * 64 + kc);
        #pragma unroll
        for (int i = 0; i < 4; ++i)
            af[i] = *(const bf16x8*)(Ab + (wm * 128 + 16 * i + fr) * 64 + kc);
        __builtin_amdgcn_s_setprio(1);
        #pragma unroll
        for (int i = 0; i < 4; ++i)
            #pragma unroll
            for (int j = 0; j < 4; ++j)
                acc[i][j] = __builtin_amdgcn_mfma_f32_16x16x32_bf16(af[i], bf[j], acc[i][j], 0, 0, 0);
        __builtin_amdgcn_s_setprio(0);
        __builtin_amdgcn_s_barrier();

        // phase 1: rows 64..127 (B frags reused in registers)
        SG_B(ts, ns);
        #pragma unroll
        for (int i = 0; i < 4; ++i)
            af[i] = *(const bf16x8*)(Ab + (wm * 128 + 64 + 16 * i + fr) * 64 + kc);
        __builtin_amdgcn_s_setprio(1);
        #pragma unroll
        for (int i = 0; i < 4; ++i)
            #pragma unroll
            for (int j = 0; j < 4; ++j)
                acc[i + 4][j] = __builtin_amdgcn_mfma_f32_16x16x32_bf16(af[i], bf[j], acc[i + 4][j], 0, 0, 0);
        __builtin_amdgcn_s_setprio(0);
    }
    #undef SG_A
    #undef SG_B

    // epilogue: exp -> fp8 P + row-sum atomics (C/D layout col=lane&15, row=(lane>>4)*4+reg)
    const int rB = (lane >> 4) << 2, cB = lane & 15;
    float psum[8][4];
    #pragma unroll
    for (int i = 0; i < 8; i++)
        #pragma unroll
        for (int t = 0; t < 4; t++) psum[i][t] = 0.f;

    #pragma unroll
    for (int i = 0; i < 8; i++) {
        const int m0 = row0 + wm * 128 + 16 * i + rB;
        #pragma unroll
        for (int j = 0; j < 4; j++) {
            const int c = col0 + wn * 64 + 16 * j + cB;
            #pragma unroll
            for (int t = 0; t < 4; t++) {
                const float e = __expf(acc[i][j][t] * scale);
                psum[i][t] += e;
                P[(size_t)(m0 + t) * 4096 + c] = f2fp8(e);
            }
        }
    }
    #pragma unroll
    for (int i = 0; i < 8; i++) {
        #pragma unroll
        for (int t = 0; t < 4; t++) {
            float v = psum[i][t];
            v += __shfl_xor(v, 1, 64);
            v += __shfl_xor(v, 2, 64);
            v += __shfl_xor(v, 4, 64);
            v += __shfl_xor(v, 8, 64);
            if (cB == 0)
                atomicAdd(&sm[row0 + wm * 128 + 16 * i + rB + t], v);
        }
    }
}

// ---------------------------------------------------------------- batched PV, fp8, same ring-4 schedule
// O[b][m][e] = sum_n P[m][n] Vt[e][n] / rowsum.  256x256 tile, K-tile = 64 fp8, 64 tiles.
// grid (16,4,4) = 256 blocks = exactly 1/CU.
__global__ __launch_bounds__(512, 2)
void pv8(const u8* __restrict__ p0, const u8* __restrict__ p1,
         const u8* __restrict__ p2, const u8* __restrict__ p3,
         const u8* __restrict__ vt8, const float* __restrict__ sums,
         float* __restrict__ out)
{
    __shared__ u8 smem[131072];     // 4 slots x (A 16KB + B 16KB)
    const int b = blockIdx.z;
    const u8* Pb = (b == 0) ? p0 : (b == 1) ? p1 : (b == 2) ? p2 : p3;
    const u8* Vb = vt8 + (size_t)b * 4194304;
    const float* sm = sums + (b << 12);
    float* Ob = out + (size_t)b * 4194304;

    const int tid = threadIdx.x;
    const int wv = tid >> 6, lane = tid & 63;
    const int wm = wv >> 2, wn = wv & 3;
    const int row0 = blockIdx.x << 8, col0 = blockIdx.y << 8;

    const int srow = tid >> 2;
    const int sc16 = ((tid & 3) ^ ((tid >> 3) & 3)) << 4;    // swizzled 16B chunk (bytes)
    const u8* gA = Pb + (size_t)(row0 + srow) * 4096 + sc16;
    const u8* gB = Vb + (size_t)(col0 + srow) * 4096 + sc16;
    char* lds = (char*)smem;
    const int wvo = wv << 10;

    const int fr = lane & 15, g = lane >> 4;
    const int sw = (fr >> 1) & 3;
    const int g2 = g >> 1, h8 = (g & 1) << 3;
    const int pc0 = ((g2 ^ sw) << 4) + h8;          // kk=0 swizzled byte offset in 64B row
    const int pc1 = (((2 + g2) ^ sw) << 4) + h8;    // kk=1

    f32x4 acc[8][4];
    #pragma unroll
    for (int i = 0; i < 8; i++)
        #pragma unroll
        for (int j = 0; j < 4; j++) acc[i][j] = (f32x4){0.f, 0.f, 0.f, 0.f};

    #define PG_A(ts, sl) { \
        gl2lds16(gA + (ts) * 64,          lds + (sl) * 32768 + wvo); \
        gl2lds16(gA + 524288 + (ts) * 64, lds + (sl) * 32768 + 8192 + wvo); }
    #define PG_B(ts, sl) { \
        gl2lds16(gB + (ts) * 64,          lds + (sl) * 32768 + 16384 + wvo); \
        gl2lds16(gB + 524288 + (ts) * 64, lds + (sl) * 32768 + 24576 + wvo); }

    PG_A(0, 0); PG_B(0, 0);
    PG_A(1, 1); PG_B(1, 1);
    PG_A(2, 2); PG_B(2, 2);

    for (int t = 0; t < 64; ++t) {
        const int slot = t & 3;
        const int ts = (t + 3) & 63;
        const int ns = (t + 3) & 3;
        const char* Ab = lds + slot * 32768;
        const char* Bb = Ab + 16384;

        asm volatile("s_waitcnt vmcnt(8)" ::: "memory");
        __builtin_amdgcn_s_barrier();
        __builtin_amdgcn_sched_barrier(0);

        // phase 0: kk = 0
        PG_A(ts, ns);
        i64 af[8], bf[4];
        #pragma unroll
        for (int i = 0; i < 8; ++i) af[i] = *(const i64*)(Ab + (wm * 128 + 16 * i + fr) * 64 + pc0);
        #pragma unroll
        for (int j = 0; j < 4; ++j) bf[j] = *(const i64*)(Bb + (wn * 64 + 16 * j + fr) * 64 + pc0);
        __builtin_amdgcn_s_setprio(1);
        #pragma unroll
        for (int i = 0; i < 8; ++i)
            #pragma unroll
            for (int j = 0; j < 4; ++j)
                acc[i][j] = __builtin_amdgcn_mfma_f32_16x16x32_fp8_fp8(af[i], bf[j], acc[i][j], 0, 0, 0);
        __builtin_amdgcn_s_setprio(0);
        __builtin_amdgcn_s_barrier();

        // phase 1: kk = 1
        PG_B(ts, ns);
        #pragma unroll
        for (int i = 0; i < 8; ++i) af[i] = *(const i64*)(Ab + (wm * 128 + 16 * i + fr) * 64 + pc1);
        #pragma unroll
        for (int j = 0; j < 4; ++j) bf[j] = *(const i64*)(Bb + (wn * 64 + 16 * j + fr) * 64 + pc1);
        __builtin_amdgcn_s_setprio(1);
        #pragma unroll
        for (int i = 0; i < 8; ++i)
            #pragma unroll
            for (int j = 0; j < 4; ++j)
                acc[i][j] = __builtin_amdgcn_mfma_f32_16x16x32_fp8_fp8(af[i], bf[j], acc[i][j], 0, 0, 0);
        __builtin_amdgcn_s_setprio(0);
    }
    #undef PG_A
    #undef PG_B

    const int rB = (lane >> 4) << 2, cB = lane & 15;
    #pragma unroll
    for (int i = 0; i < 8; i++) {
        const int m0 = row0 + wm * 128 + 16 * i + rB;
        const float i0 = 1.0f / sm[m0];
        const float i1 = 1.0f / sm[m0 + 1];
        const float i2 = 1.0f / sm[m0 + 2];
        const float i3 = 1.0f / sm[m0 + 3];
        #pragma unroll
        for (int j = 0; j < 4; j++) {
            const int e = col0 + wn * 64 + 16 * j + cB;
            Ob[(size_t)(m0 + 0) * 1024 + e] = acc[i][j][0] * i0;
            Ob[(size_t)(m0 + 1) * 1024 + e] = acc[i][j][1] * i1;
            Ob[(size_t)(m0 + 2) * 1024 + e] = acc[i][j][2] * i2;
            Ob[(size_t)(m0 + 3) * 1024 + e] = acc[i][j][3] * i3;
        }
    }
}

// ---------------------------------------------------------------- residual + LayerNorm (in place on out)
__global__ __launch_bounds__(256)
void residual_ln(const float* __restrict__ emb, float* __restrict__ out,
                 const float* __restrict__ gamma, const float* __restrict__ beta) {
    const size_t row = blockIdx.x;
    const int t = threadIdx.x;
    const int wv = t >> 6, lane = t & 63;
    const size_t base = row * 1024 + t * 4;

    float4 ev = *(const float4*)(emb + base);
    float4 ov = *(const float4*)(out + base);
    float x0 = ev.x + ov.x, x1 = ev.y + ov.y, x2 = ev.z + ov.z, x3 = ev.w + ov.w;

    float s = x0 + x1 + x2 + x3;
    float q = x0 * x0 + x1 * x1 + x2 * x2 + x3 * x3;
    s = wred_sum(s);
    q = wred_sum(q);
    __shared__ float s1[4], s2[4];
    if (lane == 0) { s1[wv] = s; s2[wv] = q; }
    __syncthreads();
    s = s1[0] + s1[1] + s1[2] + s1[3];
    q = s2[0] + s2[1] + s2[2] + s2[3];

    const float mu  = s * (1.0f / 1024.0f);
    const float var = q * (1.0f / 1024.0f) - mu * mu;
    const float r   = rsqrtf(var + 1e-5f);

    float4 g  = *(const float4*)(gamma + t * 4);
    float4 be = *(const float4*)(beta + t * 4);
    float4 res;
    res.x = (x0 - mu) * r * g.x + be.x;
    res.y = (x1 - mu) * r * g.y + be.y;
    res.z = (x2 - mu) * r * g.z + be.z;
    res.w = (x3 - mu) * r * g.w + be.w;
    *(float4*)(out + base) = res;
}

// ---------------------------------------------------------------- launch
extern "C" void kernel_launch(void* const* d_in, const int* in_sizes, int n_in,
                              void* d_out, int out_size, void* d_ws, size_t ws_size,
                              hipStream_t stream) {
    const float* emb   = (const float*)d_in[0];
    const float* Wq    = (const float*)d_in[4];
    const float* bq    = (const float*)d_in[5];
    const float* Wk    = (const float*)d_in[6];
    const float* bk    = (const float*)d_in[7];
    const float* Wv    = (const float*)d_in[8];
    const float* bv    = (const float*)d_in[9];
    const float* gamma = (const float*)d_in[10];
    const float* beta  = (const float*)d_in[11];
    float* out = (float*)d_out;

    char* ws = (char*)d_ws;
    // ws layout (bytes), with time-based reuse:
    //   [0,          33554432)  phase1: Xbf bf16 [16384,1024]
    //                           phase2: VT8 fp8 [4][1024][4096] at 0 (16,777,216)
    //                                   P0  fp8 [4096,4096]     at 16,777,216
    //   [33554432,   39845888)  phase1: Wbf bf16 [3072,1024]
    //                           phase2: sums f32 [4][4096] at 33,554,432 (65,536 B)
    //   [39845888,   73400320)  Qbf bf16 [4][4096,1024]; Q0Q1 dead after S(1) -> P3
    //   [73400320,  106954752)  Kbf bf16 [4][4096,1024]
    //   [106954752, 140509184)  phase1: Vt bf16 [4][1024][4096]
    //                           phase2 (after cast_v_fp8): P1, P2 fp8
    if (ws_size < 140509184u) return;
    u16* Xbf = (u16*)(ws);
    u16* Wbf = (u16*)(ws + 33554432);
    u16* Qbf = (u16*)(ws + 39845888);
    u16* Kbf = (u16*)(ws + 73400320);
    u16* VTB = (u16*)(ws + 106954752);

    u8*    VT8  = (u8*)(ws);
    u8*    P0   = (u8*)(ws + 16777216);
    float* SUMS = (float*)(ws + 33554432);
    u8*    P1   = (u8*)(ws + 106954752);
    u8*    P2   = (u8*)(ws + 123731968);
    u8*    P3   = (u8*)(ws + 39845888);
    u8*    Pb[4] = {P0, P1, P2, P3};

    cast_bf16<<<16384, 256, 0, stream>>>(emb, Xbf, 4194304);
    cast_bf16<<<1024, 256, 0, stream>>>(Wq, Wbf,           262144);
    cast_bf16<<<1024, 256, 0, stream>>>(Wk, Wbf + 1048576, 262144);
    cast_bf16<<<1024, 256, 0, stream>>>(Wv, Wbf + 2097152, 262144);

    // fused QKV projection: [16384,3072] = Xbf @ Wbf^T + bias; V transposed to VTB (bf16)
    gemm_bt<0, 128, true><<<dim3(128, 24), 256, 0, stream>>>(Xbf, Wbf, 1024,
        Qbf, Kbf, VTB, bq, bk, bv, nullptr, nullptr, 1.0f);

    // V bf16 -> fp8 (VTB dead afterwards; its space becomes P1/P2)
    cast_v_fp8<<<8192, 256, 0, stream>>>(VTB, VT8, 2097152);

    // zero the softmax-denominator accumulators (Wbf dead after QKV)
    hipMemsetAsync(SUMS, 0, 65536, stream);

    // S(b) = exp(Q_b K_b^T / 32) -> fp8 P_b + row sums.
    // NOTE: must stay 4 stream-ordered launches — P3 aliases Q batches 0/1.
    for (int b = 0; b < 4; ++b) {
        const size_t o = (size_t)b * 4194304;
        gemm_s8<<<dim3(16, 16), 512, 0, stream>>>(Qbf + o, Kbf + o,
            Pb[b], SUMS + b * 4096, 0.03125f);
    }

    // batched PV: O[b] = (P_b @ V_b) / rowsum -> fp32 out
    pv8<<<dim3(16, 4, 4), 512, 0, stream>>>(P0, P1, P2, P3, VT8, SUMS, out);

    residual_ln<<<16384, 256, 0, stream>>>(emb, out, gamma, beta);
}

// Round 2
// 589.455 us; speedup vs baseline: 1.0213x; 1.0213x over previous
//
#include <hip/hip_runtime.h>
#include <hip/hip_fp8.h>

typedef unsigned short u16;
typedef unsigned char  u8;
typedef long long      i64;
using bf16x8 = __attribute__((ext_vector_type(8))) __bf16;
using f32x4  = __attribute__((ext_vector_type(4))) float;

__device__ __forceinline__ u16 f2bf(float f) {
    unsigned u = __builtin_bit_cast(unsigned, f);
    u += 0x7fffu + ((u >> 16) & 1u);
    return (u16)(u >> 16);
}
__device__ __forceinline__ float bf2f(u16 h) {
    unsigned u = ((unsigned)h) << 16;
    return __builtin_bit_cast(float, u);
}
__device__ __forceinline__ u8 f2fp8(float f) {
    __hip_fp8_e4m3 t(f);
    return t.__x;
}
__device__ __forceinline__ float wred_sum(float v) {
    #pragma unroll
    for (int o = 32; o; o >>= 1) v += __shfl_xor(v, o, 64);
    return v;
}

// async global->LDS, 16B per lane. LDS dest must be wave-uniform base + lane*16.
__device__ __forceinline__ void gl2lds16(const void* g, void* l) {
    __builtin_amdgcn_global_load_lds(
        (__attribute__((address_space(1))) void*)(g),
        (__attribute__((address_space(3))) void*)(l), 16, 0, 0);
}

// ---------------------------------------------------------------- cast fp32->bf16
__global__ __launch_bounds__(256)
void cast_bf16(const float* __restrict__ src, u16* __restrict__ dst, int n4) {
    int i = blockIdx.x * 256 + threadIdx.x;
    if (i < n4) {
        float4 f = ((const float4*)src)[i];
        ushort4 u;
        u.x = f2bf(f.x); u.y = f2bf(f.y); u.z = f2bf(f.z); u.w = f2bf(f.w);
        ((ushort4*)dst)[i] = u;
    }
}

// ---------------------------------------------------------------- cast bf16 -> fp8 e4m3 (8 elems/thread)
__global__ __launch_bounds__(256)
void cast_v_fp8(const u16* __restrict__ src, u8* __restrict__ dst, int n8) {
    int i = blockIdx.x * 256 + threadIdx.x;
    if (i < n8) {
        ushort4 a = ((const ushort4*)src)[2 * i];
        ushort4 b = ((const ushort4*)src)[2 * i + 1];
        union { u8 c[8]; unsigned long long q; } r;
        r.c[0] = f2fp8(bf2f(a.x)); r.c[1] = f2fp8(bf2f(a.y));
        r.c[2] = f2fp8(bf2f(a.z)); r.c[3] = f2fp8(bf2f(a.w));
        r.c[4] = f2fp8(bf2f(b.x)); r.c[5] = f2fp8(bf2f(b.y));
        r.c[6] = f2fp8(bf2f(b.z)); r.c[7] = f2fp8(bf2f(b.w));
        ((unsigned long long*)dst)[i] = r.q;
    }
}

// ---------------------------------------------------------------- unified 256x256 bf16 GEMM, K=1024
// C = A * Bt^T. 512 threads (8 waves 2Mx4N), BK=32, ring-4 LDS (128 KiB).
// Phase discipline (m201-style): {prefetch-issue; ds_read-issue; [vmcnt(8) in phase B];
//   sched_barrier; s_barrier; lgkmcnt(0); sched_barrier; setprio(1); pure 16xMFMA; setprio(0)}.
// Slot t+1 is published by tile t phase-B's barrier (one full phase before first read).
// vmcnt never drains to 0 inside the loop (counted: oldest 4 of <=12 outstanding).
// MODE 0: QKV projection epilogue (bias; Q,K bf16; V transposed via 128KB LDS to Vt bf16).
// MODE 1: P = exp(acc*scale) -> fp8 e4m3 [.,4096] + atomic row-sum accumulation.
template<int MODE>
__global__ __launch_bounds__(512, 2)
void gemm256(const u16* __restrict__ A, const u16* __restrict__ Bt,
             u16* __restrict__ oQ, u16* __restrict__ oK, u16* __restrict__ oVt,
             const float* __restrict__ bQ, const float* __restrict__ bK,
             const float* __restrict__ bV,
             u8* __restrict__ oP, float* __restrict__ sums, const float scale)
{
    __shared__ u16 smem[65536];     // 128 KiB: 4 ring slots x (A 16KB + B 16KB); reused by V-transpose
    const int tid = threadIdx.x;
    const int wv = tid >> 6, lane = tid & 63;
    const int wm = wv >> 2, wn = wv & 3;
    const int row0 = blockIdx.x << 8, col0 = blockIdx.y << 8;

    const int srow = tid >> 2;                               // 0..127
    const int scol = ((tid & 3) ^ ((tid >> 3) & 3)) << 3;    // swizzled 16B chunk (elems)
    const u16* gA = A  + (size_t)(row0 + srow) * 1024 + scol;
    const u16* gB = Bt + (size_t)(col0 + srow) * 1024 + scol;
    char* lds = (char*)smem;
    const int wvo = wv << 10;

    const int fr = lane & 15, g = lane >> 4;
    const int kc = (g ^ ((fr >> 1) & 3)) << 4;               // swizzled chunk byte offset

    f32x4 acc[8][4];
    #pragma unroll
    for (int i = 0; i < 8; i++)
        #pragma unroll
        for (int j = 0; j < 4; j++) acc[i][j] = (f32x4){0.f, 0.f, 0.f, 0.f};

    #define SG_A(ts, sl) { \
        gl2lds16(gA + (ts) * 32,          lds + (sl) * 32768 + wvo); \
        gl2lds16(gA + 131072 + (ts) * 32, lds + (sl) * 32768 + 8192 + wvo); }
    #define SG_B(ts, sl) { \
        gl2lds16(gB + (ts) * 32,          lds + (sl) * 32768 + 16384 + wvo); \
        gl2lds16(gB + 131072 + (ts) * 32, lds + (sl) * 32768 + 24576 + wvo); }

    SG_A(0, 0); SG_B(0, 0);
    SG_A(1, 1); SG_B(1, 1);
    SG_A(2, 2); SG_B(2, 2);
    asm volatile("s_waitcnt vmcnt(8)" ::: "memory");   // own slot-0 loads drained
    __builtin_amdgcn_s_barrier();                      // publish slot 0

    for (int t = 0; t < 32; ++t) {
        const int slot = t & 3;
        const int ts = (t + 3) & 31;      // tail wraps to 0..2: redundant but safe
        const int ns = (t + 3) & 3;       // slot retired by tile t-1
        const char* Ab = lds + slot * 32768;
        const char* Bb = Ab + 16384;

        // ---- phase A: B frags + A rows 0..63 of this wave's half
        SG_A(ts, ns);
        bf16x8 bf[4], af[4];
        #pragma unroll
        for (int j = 0; j < 4; ++j)
            bf[j] = *(const bf16x8*)(Bb + (wn * 64 + 16 * j + fr) * 64 + kc);
        #pragma unroll
        for (int i = 0; i < 4; ++i)
            af[i] = *(const bf16x8*)(Ab + (wm * 128 + 16 * i + fr) * 64 + kc);
        __builtin_amdgcn_sched_barrier(0);
        __builtin_amdgcn_s_barrier();
        asm volatile("s_waitcnt lgkmcnt(0)" ::: "memory");
        __builtin_amdgcn_sched_barrier(0);
        __builtin_amdgcn_s_setprio(1);
        #pragma unroll
        for (int i = 0; i < 4; ++i)
            #pragma unroll
            for (int j = 0; j < 4; ++j)
                acc[i][j] = __builtin_amdgcn_mfma_f32_16x16x32_bf16(af[i], bf[j], acc[i][j], 0, 0, 0);
        __builtin_amdgcn_s_setprio(0);

        // ---- phase B: A rows 64..127; publish slot t+1
        SG_B(ts, ns);
        bf16x8 af2[4];
        #pragma unroll
        for (int i = 0; i < 4; ++i)
            af2[i] = *(const bf16x8*)(Ab + (wm * 128 + 64 + 16 * i + fr) * 64 + kc);
        // outstanding <=12 (slots t+1,t+2,t+3); oldest 4 = slot t+1 (issued at tile t-2)
        asm volatile("s_waitcnt vmcnt(8)" ::: "memory");
        __builtin_amdgcn_sched_barrier(0);
        __builtin_amdgcn_s_barrier();                  // publishes slot t+1 to all waves
        asm volatile("s_waitcnt lgkmcnt(0)" ::: "memory");
        __builtin_amdgcn_sched_barrier(0);
        __builtin_amdgcn_s_setprio(1);
        #pragma unroll
        for (int i = 0; i < 4; ++i)
            #pragma unroll
            for (int j = 0; j < 4; ++j)
                acc[i + 4][j] = __builtin_amdgcn_mfma_f32_16x16x32_bf16(af2[i], bf[j], acc[i + 4][j], 0, 0, 0);
        __builtin_amdgcn_s_setprio(0);
    }
    #undef SG_A
    #undef SG_B

    // drain tail prefetch DMAs BEFORE smem reuse / kernel end
    asm volatile("s_waitcnt vmcnt(0)" ::: "memory");

    const int rB = (lane >> 4) << 2, cB = lane & 15;

    if (MODE == 0) {
        const int sel = col0 >> 10;     // 0=Q 1=K 2=V  (col tiles are 1024-aligned groups of 4)
        if (sel < 2) {
            const float* bias = (sel == 0) ? bQ : bK;
            u16* dst = (sel == 0) ? oQ : oK;
            #pragma unroll
            for (int i = 0; i < 8; i++) {
                #pragma unroll
                for (int j = 0; j < 4; j++) {
                    const int m0 = row0 + wm * 128 + 16 * i + rB;
                    const int e  = (col0 & 1023) + wn * 64 + 16 * j + cB;
                    const float bb = bias[e];
                    #pragma unroll
                    for (int t = 0; t < 4; t++)
                        dst[(size_t)(m0 + t) * 1024 + e] = f2bf(acc[i][j][t] + bb);
                }
            }
        } else {
            // V: transpose full 256x256 tile through the 128KB LDS (chunk-XOR swizzle),
            // write Vt[b][e][n] bf16.
            const int b      = row0 >> 12;
            const int n_base = row0 & 4095;
            const int e0     = col0 & 1023;
            __syncthreads();            // all waves done reading ring slots (+ DMAs drained)
            #pragma unroll
            for (int i = 0; i < 8; i++) {
                const int n_l0 = wm * 128 + 16 * i + rB;
                const int hq   = n_l0 >> 3;       // 16B chunk along n (8 bf16)
                const int off  = n_l0 & 7;        // 0 or 4 -> 8B aligned
                #pragma unroll
                for (int j = 0; j < 4; j++) {
                    const int e_p = wn * 64 + 16 * j + cB;
                    const int hp  = hq ^ (e_p & 7);
                    const float bb = bV[e0 + e_p];
                    ushort4 pk;
                    pk.x = f2bf(acc[i][j][0] + bb);
                    pk.y = f2bf(acc[i][j][1] + bb);
                    pk.z = f2bf(acc[i][j][2] + bb);
                    pk.w = f2bf(acc[i][j][3] + bb);
                    *(ushort4*)&smem[e_p * 256 + hp * 8 + off] = pk;
                }
            }
            __syncthreads();
            #pragma unroll
            for (int it = 0; it < 16; ++it) {
                const int idx = it * 512 + tid;
                const int er  = idx >> 5;         // e row 0..255
                const int c   = idx & 31;         // logical 16B chunk (8 n's)
                const int cc  = c ^ (er & 7);
                int4 v = *(const int4*)&smem[er * 256 + cc * 8];
                *(int4*)&oVt[(size_t)b * 4194304 +
                             (size_t)(e0 + er) * 4096 + n_base + c * 8] = v;
            }
        }
    } else {
        // MODE 1: exp -> fp8 P + row-sum atomics (C/D layout col=lane&15, row=(lane>>4)*4+reg)
        float psum[8][4];
        #pragma unroll
        for (int i = 0; i < 8; i++)
            #pragma unroll
            for (int t = 0; t < 4; t++) psum[i][t] = 0.f;

        #pragma unroll
        for (int i = 0; i < 8; i++) {
            const int m0 = row0 + wm * 128 + 16 * i + rB;
            #pragma unroll
            for (int j = 0; j < 4; j++) {
                const int c = col0 + wn * 64 + 16 * j + cB;
                #pragma unroll
                for (int t = 0; t < 4; t++) {
                    const float e = __expf(acc[i][j][t] * scale);
                    psum[i][t] += e;
                    oP[(size_t)(m0 + t) * 4096 + c] = f2fp8(e);
                }
            }
        }
        #pragma unroll
        for (int i = 0; i < 8; i++) {
            #pragma unroll
            for (int t = 0; t < 4; t++) {
                float v = psum[i][t];
                v += __shfl_xor(v, 1, 64);
                v += __shfl_xor(v, 2, 64);
                v += __shfl_xor(v, 4, 64);
                v += __shfl_xor(v, 8, 64);
                if (cB == 0)
                    atomicAdd(&sums[row0 + wm * 128 + 16 * i + rB + t], v);
            }
        }
    }
}

// ---------------------------------------------------------------- batched PV, fp8, same phase discipline
// O[b][m][e] = sum_n P[m][n] Vt[e][n] / rowsum. 256x256 tile, K-tile = 64 fp8, 64 tiles.
// grid (16,4,4) = 256 blocks = exactly 1/CU; same-x blocks share XCD -> P panel L2-pinned.
__global__ __launch_bounds__(512, 2)
void pv256(const u8* __restrict__ p0, const u8* __restrict__ p1,
           const u8* __restrict__ p2, const u8* __restrict__ p3,
           const u8* __restrict__ vt8, const float* __restrict__ sums,
           float* __restrict__ out)
{
    __shared__ u8 smem[131072];     // 4 slots x (A 16KB + B 16KB)
    const int b = blockIdx.z;
    const u8* Pb = (b == 0) ? p0 : (b == 1) ? p1 : (b == 2) ? p2 : p3;
    const u8* Vb = vt8 + (size_t)b * 4194304;
    const float* sm = sums + (b << 12);
    float* Ob = out + (size_t)b * 4194304;

    const int tid = threadIdx.x;
    const int wv = tid >> 6, lane = tid & 63;
    const int wm = wv >> 2, wn = wv & 3;
    const int row0 = blockIdx.x << 8, col0 = blockIdx.y << 8;

    const int srow = tid >> 2;
    const int sc16 = ((tid & 3) ^ ((tid >> 3) & 3)) << 4;    // swizzled 16B chunk (bytes)
    const u8* gA = Pb + (size_t)(row0 + srow) * 4096 + sc16;
    const u8* gB = Vb + (size_t)(col0 + srow) * 4096 + sc16;
    char* lds = (char*)smem;
    const int wvo = wv << 10;

    const int fr = lane & 15, g = lane >> 4;
    const int sw = (fr >> 1) & 3;
    const int g2 = g >> 1, h8 = (g & 1) << 3;
    const int pc0 = ((g2 ^ sw) << 4) + h8;          // kk=0 swizzled byte offset in 64B row
    const int pc1 = (((2 + g2) ^ sw) << 4) + h8;    // kk=1

    f32x4 acc[8][4];
    #pragma unroll
    for (int i = 0; i < 8; i++)
        #pragma unroll
        for (int j = 0; j < 4; j++) acc[i][j] = (f32x4){0.f, 0.f, 0.f, 0.f};

    #define PG_A(ts, sl) { \
        gl2lds16(gA + (ts) * 64,          lds + (sl) * 32768 + wvo); \
        gl2lds16(gA + 524288 + (ts) * 64, lds + (sl) * 32768 + 8192 + wvo); }
    #define PG_B(ts, sl) { \
        gl2lds16(gB + (ts) * 64,          lds + (sl) * 32768 + 16384 + wvo); \
        gl2lds16(gB + 524288 + (ts) * 64, lds + (sl) * 32768 + 24576 + wvo); }

    PG_A(0, 0); PG_B(0, 0);
    PG_A(1, 1); PG_B(1, 1);
    PG_A(2, 2); PG_B(2, 2);
    asm volatile("s_waitcnt vmcnt(8)" ::: "memory");
    __builtin_amdgcn_s_barrier();                      // publish slot 0

    for (int t = 0; t < 64; ++t) {
        const int slot = t & 3;
        const int ts = (t + 3) & 63;
        const int ns = (t + 3) & 3;
        const char* Ab = lds + slot * 32768;
        const char* Bb = Ab + 16384;

        // ---- phase A: kk = 0
        PG_A(ts, ns);
        i64 af[8], bf[4];
        #pragma unroll
        for (int i = 0; i < 8; ++i) af[i] = *(const i64*)(Ab + (wm * 128 + 16 * i + fr) * 64 + pc0);
        #pragma unroll
        for (int j = 0; j < 4; ++j) bf[j] = *(const i64*)(Bb + (wn * 64 + 16 * j + fr) * 64 + pc0);
        __builtin_amdgcn_sched_barrier(0);
        __builtin_amdgcn_s_barrier();
        asm volatile("s_waitcnt lgkmcnt(0)" ::: "memory");
        __builtin_amdgcn_sched_barrier(0);
        __builtin_amdgcn_s_setprio(1);
        #pragma unroll
        for (int i = 0; i < 8; ++i)
            #pragma unroll
            for (int j = 0; j < 4; ++j)
                acc[i][j] = __builtin_amdgcn_mfma_f32_16x16x32_fp8_fp8(af[i], bf[j], acc[i][j], 0, 0, 0);
        __builtin_amdgcn_s_setprio(0);

        // ---- phase B: kk = 1; publish slot t+1
        PG_B(ts, ns);
        #pragma unroll
        for (int i = 0; i < 8; ++i) af[i] = *(const i64*)(Ab + (wm * 128 + 16 * i + fr) * 64 + pc1);
        #pragma unroll
        for (int j = 0; j < 4; ++j) bf[j] = *(const i64*)(Bb + (wn * 64 + 16 * j + fr) * 64 + pc1);
        asm volatile("s_waitcnt vmcnt(8)" ::: "memory");
        __builtin_amdgcn_sched_barrier(0);
        __builtin_amdgcn_s_barrier();
        asm volatile("s_waitcnt lgkmcnt(0)" ::: "memory");
        __builtin_amdgcn_sched_barrier(0);
        __builtin_amdgcn_s_setprio(1);
        #pragma unroll
        for (int i = 0; i < 8; ++i)
            #pragma unroll
            for (int j = 0; j < 4; ++j)
                acc[i][j] = __builtin_amdgcn_mfma_f32_16x16x32_fp8_fp8(af[i], bf[j], acc[i][j], 0, 0, 0);
        __builtin_amdgcn_s_setprio(0);
    }
    #undef PG_A
    #undef PG_B

    asm volatile("s_waitcnt vmcnt(0)" ::: "memory");   // drain tail prefetch DMAs

    const int rB = (lane >> 4) << 2, cB = lane & 15;
    #pragma unroll
    for (int i = 0; i < 8; i++) {
        const int m0 = row0 + wm * 128 + 16 * i + rB;
        const float i0 = 1.0f / sm[m0];
        const float i1 = 1.0f / sm[m0 + 1];
        const float i2 = 1.0f / sm[m0 + 2];
        const float i3 = 1.0f / sm[m0 + 3];
        #pragma unroll
        for (int j = 0; j < 4; j++) {
            const int e = col0 + wn * 64 + 16 * j + cB;
            Ob[(size_t)(m0 + 0) * 1024 + e] = acc[i][j][0] * i0;
            Ob[(size_t)(m0 + 1) * 1024 + e] = acc[i][j][1] * i1;
            Ob[(size_t)(m0 + 2) * 1024 + e] = acc[i][j][2] * i2;
            Ob[(size_t)(m0 + 3) * 1024 + e] = acc[i][j][3] * i3;
        }
    }
}

// ---------------------------------------------------------------- residual + LayerNorm (in place on out)
__global__ __launch_bounds__(256)
void residual_ln(const float* __restrict__ emb, float* __restrict__ out,
                 const float* __restrict__ gamma, const float* __restrict__ beta) {
    const size_t row = blockIdx.x;
    const int t = threadIdx.x;
    const int wv = t >> 6, lane = t & 63;
    const size_t base = row * 1024 + t * 4;

    float4 ev = *(const float4*)(emb + base);
    float4 ov = *(const float4*)(out + base);
    float x0 = ev.x + ov.x, x1 = ev.y + ov.y, x2 = ev.z + ov.z, x3 = ev.w + ov.w;

    float s = x0 + x1 + x2 + x3;
    float q = x0 * x0 + x1 * x1 + x2 * x2 + x3 * x3;
    s = wred_sum(s);
    q = wred_sum(q);
    __shared__ float s1[4], s2[4];
    if (lane == 0) { s1[wv] = s; s2[wv] = q; }
    __syncthreads();
    s = s1[0] + s1[1] + s1[2] + s1[3];
    q = s2[0] + s2[1] + s2[2] + s2[3];

    const float mu  = s * (1.0f / 1024.0f);
    const float var = q * (1.0f / 1024.0f) - mu * mu;
    const float r   = rsqrtf(var + 1e-5f);

    float4 g  = *(const float4*)(gamma + t * 4);
    float4 be = *(const float4*)(beta + t * 4);
    float4 res;
    res.x = (x0 - mu) * r * g.x + be.x;
    res.y = (x1 - mu) * r * g.y + be.y;
    res.z = (x2 - mu) * r * g.z + be.z;
    res.w = (x3 - mu) * r * g.w + be.w;
    *(float4*)(out + base) = res;
}

// ---------------------------------------------------------------- launch
extern "C" void kernel_launch(void* const* d_in, const int* in_sizes, int n_in,
                              void* d_out, int out_size, void* d_ws, size_t ws_size,
                              hipStream_t stream) {
    const float* emb   = (const float*)d_in[0];
    const float* Wq    = (const float*)d_in[4];
    const float* bq    = (const float*)d_in[5];
    const float* Wk    = (const float*)d_in[6];
    const float* bk    = (const float*)d_in[7];
    const float* Wv    = (const float*)d_in[8];
    const float* bv    = (const float*)d_in[9];
    const float* gamma = (const float*)d_in[10];
    const float* beta  = (const float*)d_in[11];
    float* out = (float*)d_out;

    char* ws = (char*)d_ws;
    // ws layout (bytes), with time-based reuse:
    //   [0,          33554432)  phase1: Xbf bf16 [16384,1024]
    //                           phase2: VT8 fp8 [4][1024][4096] at 0 (16,777,216)
    //                                   P0  fp8 [4096,4096]     at 16,777,216
    //   [33554432,   39845888)  phase1: Wbf bf16 [3072,1024]
    //                           phase2: sums f32 [4][4096] at 33,554,432 (65,536 B)
    //   [39845888,   73400320)  Qbf bf16 [4][4096,1024]; Q0Q1 dead after S(1) -> P3
    //   [73400320,  106954752)  Kbf bf16 [4][4096,1024]
    //   [106954752, 140509184)  phase1: Vt bf16 [4][1024][4096]
    //                           phase2 (after cast_v_fp8): P1, P2 fp8
    if (ws_size < 140509184u) return;
    u16* Xbf = (u16*)(ws);
    u16* Wbf = (u16*)(ws + 33554432);
    u16* Qbf = (u16*)(ws + 39845888);
    u16* Kbf = (u16*)(ws + 73400320);
    u16* VTB = (u16*)(ws + 106954752);

    u8*    VT8  = (u8*)(ws);
    u8*    P0   = (u8*)(ws + 16777216);
    float* SUMS = (float*)(ws + 33554432);
    u8*    P1   = (u8*)(ws + 106954752);
    u8*    P2   = (u8*)(ws + 123731968);
    u8*    P3   = (u8*)(ws + 39845888);
    u8*    Pb[4] = {P0, P1, P2, P3};

    cast_bf16<<<16384, 256, 0, stream>>>(emb, Xbf, 4194304);
    cast_bf16<<<1024, 256, 0, stream>>>(Wq, Wbf,           262144);
    cast_bf16<<<1024, 256, 0, stream>>>(Wk, Wbf + 1048576, 262144);
    cast_bf16<<<1024, 256, 0, stream>>>(Wv, Wbf + 2097152, 262144);

    // fused QKV projection: [16384,3072] = Xbf @ Wbf^T + bias; V transposed to VTB (bf16)
    // grid x = row tiles (64), y = col tiles (12): same-X blocks share XCD -> X panel L2-pinned.
    gemm256<0><<<dim3(64, 12), 512, 0, stream>>>(Xbf, Wbf,
        Qbf, Kbf, VTB, bq, bk, bv, nullptr, nullptr, 1.0f);

    // V bf16 -> fp8 (VTB dead afterwards; its space becomes P1/P2)
    cast_v_fp8<<<8192, 256, 0, stream>>>(VTB, VT8, 2097152);

    // zero the softmax-denominator accumulators (Wbf dead after QKV)
    hipMemsetAsync(SUMS, 0, 65536, stream);

    // S(b) = exp(Q_b K_b^T / 32) -> fp8 P_b + row sums.
    // NOTE: must stay 4 stream-ordered launches — P3 aliases Q batches 0/1.
    for (int b = 0; b < 4; ++b) {
        const size_t o = (size_t)b * 4194304;
        gemm256<1><<<dim3(16, 16), 512, 0, stream>>>(Qbf + o, Kbf + o,
            nullptr, nullptr, nullptr, nullptr, nullptr, nullptr,
            Pb[b], SUMS + b * 4096, 0.03125f);
    }

    // batched PV: O[b] = (P_b @ V_b) / rowsum -> fp32 out
    pv256<<<dim3(16, 4, 4), 512, 0, stream>>>(P0, P1, P2, P3, VT8, SUMS, out);

    residual_ln<<<16384, 256, 0, stream>>>(emb, out, gamma, beta);
}

// Round 3
// 524.759 us; speedup vs baseline: 1.1472x; 1.1233x over previous
//
#include <hip/hip_runtime.h>
#include <hip/hip_fp8.h>

typedef unsigned short u16;
typedef unsigned char  u8;
typedef long long      i64;
using bf16x8 = __attribute__((ext_vector_type(8))) __bf16;
using f32x4  = __attribute__((ext_vector_type(4))) float;

__device__ __forceinline__ u16 f2bf(float f) {
    unsigned u = __builtin_bit_cast(unsigned, f);
    u += 0x7fffu + ((u >> 16) & 1u);
    return (u16)(u >> 16);
}
__device__ __forceinline__ float bf2f(u16 h) {
    unsigned u = ((unsigned)h) << 16;
    return __builtin_bit_cast(float, u);
}
__device__ __forceinline__ u8 f2fp8(float f) {
    __hip_fp8_e4m3 t(f);
    return t.__x;
}
__device__ __forceinline__ float wred_sum(float v) {
    #pragma unroll
    for (int o = 32; o; o >>= 1) v += __shfl_xor(v, o, 64);
    return v;
}

// async global->LDS, 16B per lane. LDS dest must be wave-uniform base + lane*16.
__device__ __forceinline__ void gl2lds16(const void* g, void* l) {
    __builtin_amdgcn_global_load_lds(
        (__attribute__((address_space(1))) void*)(g),
        (__attribute__((address_space(3))) void*)(l), 16, 0, 0);
}

// ---------------------------------------------------------------- cast fp32->bf16
__global__ __launch_bounds__(256)
void cast_bf16(const float* __restrict__ src, u16* __restrict__ dst, int n4) {
    int i = blockIdx.x * 256 + threadIdx.x;
    if (i < n4) {
        float4 f = ((const float4*)src)[i];
        ushort4 u;
        u.x = f2bf(f.x); u.y = f2bf(f.y); u.z = f2bf(f.z); u.w = f2bf(f.w);
        ((ushort4*)dst)[i] = u;
    }
}

// ---------------------------------------------------------------- unified 256x256 bf16 GEMM, K=1024
// C = A * Bt^T. 512 threads (8 waves 2Mx4N), BK=32, ring-4 LDS (128 KiB).
// Phase discipline: {prefetch-issue; ds_read-issue; [vmcnt(8) in phase B]; sched_barrier;
//   s_barrier; lgkmcnt(0); sched_barrier; setprio(1); pure 16xMFMA; setprio(0)}.
// Slot t+1 is published by tile t phase-B's barrier; vmcnt never drains to 0 in the loop.
// MODE 0: QKV projection epilogue. Q,K: bias -> bf16 row-major. V: bias -> fp8 e4m3,
//         transposed through LDS to Vt8[b][e][n] (oP = Vt8 base).
// MODE 1: P = exp(acc*scale) -> fp8 e4m3 [.,4096] + atomic row-sum accumulation.
//         blockIdx.z selects batch: A/Bt offset by z*4M elems, P = z? oP2 : oP,
//         sums += z*4096.
template<int MODE>
__global__ __launch_bounds__(512, 2)
void gemm256(const u16* __restrict__ A, const u16* __restrict__ Bt,
             u16* __restrict__ oQ, u16* __restrict__ oK,
             const float* __restrict__ bQ, const float* __restrict__ bK,
             const float* __restrict__ bV,
             u8* __restrict__ oP, u8* __restrict__ oP2,
             float* __restrict__ sums, const float scale)
{
    __shared__ u16 smem[65536];     // 128 KiB: 4 ring slots x (A 16KB + B 16KB); reused by epilogues
    const int tid = threadIdx.x;
    const int wv = tid >> 6, lane = tid & 63;
    const int wm = wv >> 2, wn = wv & 3;
    const int row0 = blockIdx.x << 8, col0 = blockIdx.y << 8;

    const size_t boff = (size_t)blockIdx.z * 4194304;        // MODE 1 batch select (0 otherwise)
    const int srow = tid >> 2;                               // 0..127
    const int scol = ((tid & 3) ^ ((tid >> 3) & 3)) << 3;    // swizzled 16B chunk (elems)
    const u16* gA = A + boff + (size_t)(row0 + srow) * 1024 + scol;
    const u16* gB = Bt + boff + (size_t)(col0 + srow) * 1024 + scol;
    char* lds = (char*)smem;
    const int wvo = wv << 10;

    const int fr = lane & 15, g = lane >> 4;
    const int kc = (g ^ ((fr >> 1) & 3)) << 4;               // swizzled chunk byte offset

    f32x4 acc[8][4];
    #pragma unroll
    for (int i = 0; i < 8; i++)
        #pragma unroll
        for (int j = 0; j < 4; j++) acc[i][j] = (f32x4){0.f, 0.f, 0.f, 0.f};

    #define SG_A(ts, sl) { \
        gl2lds16(gA + (ts) * 32,          lds + (sl) * 32768 + wvo); \
        gl2lds16(gA + 131072 + (ts) * 32, lds + (sl) * 32768 + 8192 + wvo); }
    #define SG_B(ts, sl) { \
        gl2lds16(gB + (ts) * 32,          lds + (sl) * 32768 + 16384 + wvo); \
        gl2lds16(gB + 131072 + (ts) * 32, lds + (sl) * 32768 + 24576 + wvo); }

    SG_A(0, 0); SG_B(0, 0);
    SG_A(1, 1); SG_B(1, 1);
    SG_A(2, 2); SG_B(2, 2);
    asm volatile("s_waitcnt vmcnt(8)" ::: "memory");   // own slot-0 loads drained
    __builtin_amdgcn_s_barrier();                      // publish slot 0

    for (int t = 0; t < 32; ++t) {
        const int slot = t & 3;
        const int ts = (t + 3) & 31;      // tail wraps to 0..2: redundant but safe
        const int ns = (t + 3) & 3;       // slot retired by tile t-1
        const char* Ab = lds + slot * 32768;
        const char* Bb = Ab + 16384;

        // ---- phase A: B frags + A rows 0..63 of this wave's half
        SG_A(ts, ns);
        bf16x8 bf[4], af[4];
        #pragma unroll
        for (int j = 0; j < 4; ++j)
            bf[j] = *(const bf16x8*)(Bb + (wn * 64 + 16 * j + fr) * 64 + kc);
        #pragma unroll
        for (int i = 0; i < 4; ++i)
            af[i] = *(const bf16x8*)(Ab + (wm * 128 + 16 * i + fr) * 64 + kc);
        __builtin_amdgcn_sched_barrier(0);
        __builtin_amdgcn_s_barrier();
        asm volatile("s_waitcnt lgkmcnt(0)" ::: "memory");
        __builtin_amdgcn_sched_barrier(0);
        __builtin_amdgcn_s_setprio(1);
        #pragma unroll
        for (int i = 0; i < 4; ++i)
            #pragma unroll
            for (int j = 0; j < 4; ++j)
                acc[i][j] = __builtin_amdgcn_mfma_f32_16x16x32_bf16(af[i], bf[j], acc[i][j], 0, 0, 0);
        __builtin_amdgcn_s_setprio(0);

        // ---- phase B: A rows 64..127; publish slot t+1
        SG_B(ts, ns);
        bf16x8 af2[4];
        #pragma unroll
        for (int i = 0; i < 4; ++i)
            af2[i] = *(const bf16x8*)(Ab + (wm * 128 + 64 + 16 * i + fr) * 64 + kc);
        // outstanding <=12 (slots t+1,t+2,t+3); oldest 4 = slot t+1 (issued at tile t-2)
        asm volatile("s_waitcnt vmcnt(8)" ::: "memory");
        __builtin_amdgcn_sched_barrier(0);
        __builtin_amdgcn_s_barrier();                  // publishes slot t+1 to all waves
        asm volatile("s_waitcnt lgkmcnt(0)" ::: "memory");
        __builtin_amdgcn_sched_barrier(0);
        __builtin_amdgcn_s_setprio(1);
        #pragma unroll
        for (int i = 0; i < 4; ++i)
            #pragma unroll
            for (int j = 0; j < 4; ++j)
                acc[i + 4][j] = __builtin_amdgcn_mfma_f32_16x16x32_bf16(af2[i], bf[j], acc[i + 4][j], 0, 0, 0);
        __builtin_amdgcn_s_setprio(0);
    }
    #undef SG_A
    #undef SG_B

    // drain tail prefetch DMAs BEFORE smem reuse / kernel end
    asm volatile("s_waitcnt vmcnt(0)" ::: "memory");

    const int rB = (lane >> 4) << 2, cB = lane & 15;

    if (MODE == 0) {
        const int sel = col0 >> 10;     // 0=Q 1=K 2=V  (col tiles are 1024-aligned groups of 4)
        if (sel < 2) {
            const float* bias = (sel == 0) ? bQ : bK;
            u16* dst = (sel == 0) ? oQ : oK;
            #pragma unroll
            for (int i = 0; i < 8; i++) {
                #pragma unroll
                for (int j = 0; j < 4; j++) {
                    const int m0 = row0 + wm * 128 + 16 * i + rB;
                    const int e  = (col0 & 1023) + wn * 64 + 16 * j + cB;
                    const float bb = bias[e];
                    #pragma unroll
                    for (int t = 0; t < 4; t++)
                        dst[(size_t)(m0 + t) * 1024 + e] = f2bf(acc[i][j][t] + bb);
                }
            }
        } else {
            // V: bias + DIRECT fp8 quantize + transpose 256x256 tile via LDS (64 KB),
            // write Vt8[b][e][n]. Lane's 4 acc rows = 4 consecutive n -> pack one dword.
            // LDS layout: [e][64 dwords], 16B-group XOR swizzle: phys_group = grp ^ (e&15).
            const int b      = row0 >> 12;
            const int n_base = row0 & 4095;
            const int e0     = col0 & 1023;
            unsigned* lds32 = (unsigned*)smem;
            __syncthreads();            // all waves done with ring slots (+ DMAs drained)
            #pragma unroll
            for (int i = 0; i < 8; i++) {
                const int n_l0 = wm * 128 + 16 * i + rB;   // multiple of 4
                const int gq   = n_l0 >> 4;                // 16B group 0..15
                const int kq   = (n_l0 >> 2) & 3;          // dword within group
                #pragma unroll
                for (int j = 0; j < 4; j++) {
                    const int e_p = wn * 64 + 16 * j + cB;
                    const float bb = bV[e0 + e_p];
                    union { u8 c[4]; unsigned u; } pk;
                    pk.c[0] = f2fp8(acc[i][j][0] + bb);
                    pk.c[1] = f2fp8(acc[i][j][1] + bb);
                    pk.c[2] = f2fp8(acc[i][j][2] + bb);
                    pk.c[3] = f2fp8(acc[i][j][3] + bb);
                    lds32[e_p * 64 + ((gq ^ (e_p & 15)) << 2) + kq] = pk.u;
                }
            }
            __syncthreads();
            #pragma unroll
            for (int it = 0; it < 8; ++it) {
                const int idx = it * 512 + tid;
                const int er  = idx >> 4;          // e row 0..255
                const int c16 = idx & 15;          // logical 16B chunk along n
                int4 v = *(const int4*)&lds32[er * 64 + ((c16 ^ (er & 15)) << 2)];
                *(int4*)&oP[(size_t)b * 4194304 +
                            (size_t)(e0 + er) * 4096 + n_base + c16 * 16] = v;
            }
        }
    } else {
        // MODE 1: exp -> fp8 P + row-sum atomics (C/D layout col=lane&15, row=(lane>>4)*4+reg)
        u8* Pz = blockIdx.z ? oP2 : oP;
        float* smz = sums + (blockIdx.z << 12);
        float psum[8][4];
        #pragma unroll
        for (int i = 0; i < 8; i++)
            #pragma unroll
            for (int t = 0; t < 4; t++) psum[i][t] = 0.f;

        #pragma unroll
        for (int i = 0; i < 8; i++) {
            const int m0 = row0 + wm * 128 + 16 * i + rB;
            #pragma unroll
            for (int j = 0; j < 4; j++) {
                const int c = col0 + wn * 64 + 16 * j + cB;
                #pragma unroll
                for (int t = 0; t < 4; t++) {
                    const float e = __expf(acc[i][j][t] * scale);
                    psum[i][t] += e;
                    Pz[(size_t)(m0 + t) * 4096 + c] = f2fp8(e);
                }
            }
        }
        #pragma unroll
        for (int i = 0; i < 8; i++) {
            #pragma unroll
            for (int t = 0; t < 4; t++) {
                float v = psum[i][t];
                v += __shfl_xor(v, 1, 64);
                v += __shfl_xor(v, 2, 64);
                v += __shfl_xor(v, 4, 64);
                v += __shfl_xor(v, 8, 64);
                if (cB == 0)
                    atomicAdd(&smz[row0 + wm * 128 + 16 * i + rB + t], v);
            }
        }
    }
}

// ---------------------------------------------------------------- batched PV, fp8, same phase discipline
// O[b][m][e] = sum_n P[m][n] Vt[e][n] / rowsum. 256x256 tile, K-tile = 64 fp8, 64 tiles.
// grid (16,4,4) = 256 blocks = exactly 1/CU.
__global__ __launch_bounds__(512, 2)
void pv256(const u8* __restrict__ p0, const u8* __restrict__ p1,
           const u8* __restrict__ p2, const u8* __restrict__ p3,
           const u8* __restrict__ vt8, const float* __restrict__ sums,
           float* __restrict__ out)
{
    __shared__ u8 smem[131072];     // 4 slots x (A 16KB + B 16KB)
    const int b = blockIdx.z;
    const u8* Pb = (b == 0) ? p0 : (b == 1) ? p1 : (b == 2) ? p2 : p3;
    const u8* Vb = vt8 + (size_t)b * 4194304;
    const float* sm = sums + (b << 12);
    float* Ob = out + (size_t)b * 4194304;

    const int tid = threadIdx.x;
    const int wv = tid >> 6, lane = tid & 63;
    const int wm = wv >> 2, wn = wv & 3;
    const int row0 = blockIdx.x << 8, col0 = blockIdx.y << 8;

    const int srow = tid >> 2;
    const int sc16 = ((tid & 3) ^ ((tid >> 3) & 3)) << 4;    // swizzled 16B chunk (bytes)
    const u8* gA = Pb + (size_t)(row0 + srow) * 4096 + sc16;
    const u8* gB = Vb + (size_t)(col0 + srow) * 4096 + sc16;
    char* lds = (char*)smem;
    const int wvo = wv << 10;

    const int fr = lane & 15, g = lane >> 4;
    const int sw = (fr >> 1) & 3;
    const int g2 = g >> 1, h8 = (g & 1) << 3;
    const int pc0 = ((g2 ^ sw) << 4) + h8;          // kk=0 swizzled byte offset in 64B row
    const int pc1 = (((2 + g2) ^ sw) << 4) + h8;    // kk=1

    f32x4 acc[8][4];
    #pragma unroll
    for (int i = 0; i < 8; i++)
        #pragma unroll
        for (int j = 0; j < 4; j++) acc[i][j] = (f32x4){0.f, 0.f, 0.f, 0.f};

    #define PG_A(ts, sl) { \
        gl2lds16(gA + (ts) * 64,          lds + (sl) * 32768 + wvo); \
        gl2lds16(gA + 524288 + (ts) * 64, lds + (sl) * 32768 + 8192 + wvo); }
    #define PG_B(ts, sl) { \
        gl2lds16(gB + (ts) * 64,          lds + (sl) * 32768 + 16384 + wvo); \
        gl2lds16(gB + 524288 + (ts) * 64, lds + (sl) * 32768 + 24576 + wvo); }

    PG_A(0, 0); PG_B(0, 0);
    PG_A(1, 1); PG_B(1, 1);
    PG_A(2, 2); PG_B(2, 2);
    asm volatile("s_waitcnt vmcnt(8)" ::: "memory");
    __builtin_amdgcn_s_barrier();                      // publish slot 0

    for (int t = 0; t < 64; ++t) {
        const int slot = t & 3;
        const int ts = (t + 3) & 63;
        const int ns = (t + 3) & 3;
        const char* Ab = lds + slot * 32768;
        const char* Bb = Ab + 16384;

        // ---- phase A: kk = 0
        PG_A(ts, ns);
        i64 af[8], bf[4];
        #pragma unroll
        for (int i = 0; i < 8; ++i) af[i] = *(const i64*)(Ab + (wm * 128 + 16 * i + fr) * 64 + pc0);
        #pragma unroll
        for (int j = 0; j < 4; ++j) bf[j] = *(const i64*)(Bb + (wn * 64 + 16 * j + fr) * 64 + pc0);
        __builtin_amdgcn_sched_barrier(0);
        __builtin_amdgcn_s_barrier();
        asm volatile("s_waitcnt lgkmcnt(0)" ::: "memory");
        __builtin_amdgcn_sched_barrier(0);
        __builtin_amdgcn_s_setprio(1);
        #pragma unroll
        for (int i = 0; i < 8; ++i)
            #pragma unroll
            for (int j = 0; j < 4; ++j)
                acc[i][j] = __builtin_amdgcn_mfma_f32_16x16x32_fp8_fp8(af[i], bf[j], acc[i][j], 0, 0, 0);
        __builtin_amdgcn_s_setprio(0);

        // ---- phase B: kk = 1; publish slot t+1
        PG_B(ts, ns);
        #pragma unroll
        for (int i = 0; i < 8; ++i) af[i] = *(const i64*)(Ab + (wm * 128 + 16 * i + fr) * 64 + pc1);
        #pragma unroll
        for (int j = 0; j < 4; ++j) bf[j] = *(const i64*)(Bb + (wn * 64 + 16 * j + fr) * 64 + pc1);
        asm volatile("s_waitcnt vmcnt(8)" ::: "memory");
        __builtin_amdgcn_sched_barrier(0);
        __builtin_amdgcn_s_barrier();
        asm volatile("s_waitcnt lgkmcnt(0)" ::: "memory");
        __builtin_amdgcn_sched_barrier(0);
        __builtin_amdgcn_s_setprio(1);
        #pragma unroll
        for (int i = 0; i < 8; ++i)
            #pragma unroll
            for (int j = 0; j < 4; ++j)
                acc[i][j] = __builtin_amdgcn_mfma_f32_16x16x32_fp8_fp8(af[i], bf[j], acc[i][j], 0, 0, 0);
        __builtin_amdgcn_s_setprio(0);
    }
    #undef PG_A
    #undef PG_B

    asm volatile("s_waitcnt vmcnt(0)" ::: "memory");   // drain tail prefetch DMAs

    const int rB = (lane >> 4) << 2, cB = lane & 15;
    #pragma unroll
    for (int i = 0; i < 8; i++) {
        const int m0 = row0 + wm * 128 + 16 * i + rB;
        const float i0 = 1.0f / sm[m0];
        const float i1 = 1.0f / sm[m0 + 1];
        const float i2 = 1.0f / sm[m0 + 2];
        const float i3 = 1.0f / sm[m0 + 3];
        #pragma unroll
        for (int j = 0; j < 4; j++) {
            const int e = col0 + wn * 64 + 16 * j + cB;
            Ob[(size_t)(m0 + 0) * 1024 + e] = acc[i][j][0] * i0;
            Ob[(size_t)(m0 + 1) * 1024 + e] = acc[i][j][1] * i1;
            Ob[(size_t)(m0 + 2) * 1024 + e] = acc[i][j][2] * i2;
            Ob[(size_t)(m0 + 3) * 1024 + e] = acc[i][j][3] * i3;
        }
    }
}

// ---------------------------------------------------------------- residual + LayerNorm (in place on out)
__global__ __launch_bounds__(256)
void residual_ln(const float* __restrict__ emb, float* __restrict__ out,
                 const float* __restrict__ gamma, const float* __restrict__ beta) {
    const size_t row = blockIdx.x;
    const int t = threadIdx.x;
    const int wv = t >> 6, lane = t & 63;
    const size_t base = row * 1024 + t * 4;

    float4 ev = *(const float4*)(emb + base);
    float4 ov = *(const float4*)(out + base);
    float x0 = ev.x + ov.x, x1 = ev.y + ov.y, x2 = ev.z + ov.z, x3 = ev.w + ov.w;

    float s = x0 + x1 + x2 + x3;
    float q = x0 * x0 + x1 * x1 + x2 * x2 + x3 * x3;
    s = wred_sum(s);
    q = wred_sum(q);
    __shared__ float s1[4], s2[4];
    if (lane == 0) { s1[wv] = s; s2[wv] = q; }
    __syncthreads();
    s = s1[0] + s1[1] + s1[2] + s1[3];
    q = s2[0] + s2[1] + s2[2] + s2[3];

    const float mu  = s * (1.0f / 1024.0f);
    const float var = q * (1.0f / 1024.0f) - mu * mu;
    const float r   = rsqrtf(var + 1e-5f);

    float4 g  = *(const float4*)(gamma + t * 4);
    float4 be = *(const float4*)(beta + t * 4);
    float4 res;
    res.x = (x0 - mu) * r * g.x + be.x;
    res.y = (x1 - mu) * r * g.y + be.y;
    res.z = (x2 - mu) * r * g.z + be.z;
    res.w = (x3 - mu) * r * g.w + be.w;
    *(float4*)(out + base) = res;
}

// ---------------------------------------------------------------- launch
extern "C" void kernel_launch(void* const* d_in, const int* in_sizes, int n_in,
                              void* d_out, int out_size, void* d_ws, size_t ws_size,
                              hipStream_t stream) {
    const float* emb   = (const float*)d_in[0];
    const float* Wq    = (const float*)d_in[4];
    const float* bq    = (const float*)d_in[5];
    const float* Wk    = (const float*)d_in[6];
    const float* bk    = (const float*)d_in[7];
    const float* Wv    = (const float*)d_in[8];
    const float* bv    = (const float*)d_in[9];
    const float* gamma = (const float*)d_in[10];
    const float* beta  = (const float*)d_in[11];
    float* out = (float*)d_out;

    char* ws = (char*)d_ws;
    // ws layout (bytes), time-based reuse:
    //   [0,          33554432)  phase1: Xbf bf16 [16384,1024]        (dead after QKV)
    //                           phase2: P0 fp8 at 0; P1 fp8 at 16777216
    //   [33554432,   39845888)  phase1: Wbf bf16 [3072,1024]         (dead after QKV)
    //                           phase2: SUMS f32 [4][4096] at 33554432
    //   [39845888,   73400320)  Qbf bf16 [4][4096,1024]; Q0,Q1 dead after S-launch-A -> P3
    //   [73400320,  106954752)  Kbf bf16 [4][4096,1024]
    //   [106954752, 123731968)  VT8 fp8 [4][1024][4096] (written directly by QKV epilogue)
    //   [123731968, 140509184)  P2 fp8
    if (ws_size < 140509184u) return;
    u16* Xbf = (u16*)(ws);
    u16* Wbf = (u16*)(ws + 33554432);
    u16* Qbf = (u16*)(ws + 39845888);
    u16* Kbf = (u16*)(ws + 73400320);

    u8*    P0   = (u8*)(ws);
    u8*    P1   = (u8*)(ws + 16777216);
    float* SUMS = (float*)(ws + 33554432);
    u8*    P3   = (u8*)(ws + 39845888);
    u8*    VT8  = (u8*)(ws + 106954752);
    u8*    P2   = (u8*)(ws + 123731968);

    cast_bf16<<<16384, 256, 0, stream>>>(emb, Xbf, 4194304);
    cast_bf16<<<1024, 256, 0, stream>>>(Wq, Wbf,           262144);
    cast_bf16<<<1024, 256, 0, stream>>>(Wk, Wbf + 1048576, 262144);
    cast_bf16<<<1024, 256, 0, stream>>>(Wv, Wbf + 2097152, 262144);

    // fused QKV projection: [16384,3072] = Xbf @ Wbf^T + bias;
    // V quantized+transposed directly to VT8 (fp8) in the epilogue.
    gemm256<0><<<dim3(64, 12), 512, 0, stream>>>(Xbf, Wbf,
        Qbf, Kbf, bq, bk, bv, VT8, nullptr, nullptr, 1.0f);

    // zero the softmax-denominator accumulators (Wbf dead after QKV)
    hipMemsetAsync(SUMS, 0, 65536, stream);

    // S(b) = exp(Q_b K_b^T / 32) -> fp8 P_b + row sums, two launches of z=2.
    // Launch A (batches 0,1) writes P0,P1 (dead Xbf region).
    gemm256<1><<<dim3(16, 16, 2), 512, 0, stream>>>(Qbf, Kbf,
        nullptr, nullptr, nullptr, nullptr, nullptr,
        P0, P1, SUMS, 0.03125f);
    // Launch B (batches 2,3) writes P2 and P3 (P3 reuses Q0/Q1, dead after launch A).
    gemm256<1><<<dim3(16, 16, 2), 512, 0, stream>>>(Qbf + 2 * 4194304, Kbf + 2 * 4194304,
        nullptr, nullptr, nullptr, nullptr, nullptr,
        P2, P3, SUMS + 8192, 0.03125f);

    // batched PV: O[b] = (P_b @ V_b) / rowsum -> fp32 out
    pv256<<<dim3(16, 4, 4), 512, 0, stream>>>(P0, P1, P2, P3, VT8, SUMS, out);

    residual_ln<<<16384, 256, 0, stream>>>(emb, out, gamma, beta);
}